// Round 5
// baseline (95.678 us; speedup 1.0000x reference)
//
#include <hip/hip_runtime.h>
#include <stdint.h>

#define NN 256
#define II 128
#define BATCH 512
#define STEPS 6
#define LOG2E 1.4426950408889634f

typedef _Float16 half_t;
typedef _Float16 h2 __attribute__((ext_vector_type(2)));
typedef unsigned short us2 __attribute__((ext_vector_type(2)));
typedef float v2f __attribute__((ext_vector_type(2)));

__device__ __forceinline__ h2 bch2(unsigned u) { return __builtin_bit_cast(h2, u); }

// ---------------- pack: per (quad, tid) entry, f16 params ----------------
// Main-kernel mapping: tid in [0,1024), q = tid&3 (i-quarter), j = tid>>2.
// Entry (ip2, tid) covers i = i0..i0+3 with i0 = q*(ni/4) + ip2*4, column j.
// pq4 = { h2{p0,p1}, h2{q0,q1}, h2{p2,p3}, h2{q2,q3} }, w2 = { h2{w0,w1}, h2{w2,w3} }
// p = -log2e*sigma ; q = log2e*sigma*mu ; w = W*erev
__global__ void pack_f16(const float* __restrict__ sigma, const float* __restrict__ mu,
                         const float* __restrict__ W, const float* __restrict__ erev,
                         uint4* __restrict__ pq4, uint2* __restrict__ w2, int ni)
{
    int gid = blockIdx.x * blockDim.x + threadIdx.x;
    int total = (ni / 16) * 1024;
    if (gid >= total) return;
    int ip2 = gid >> 10, t = gid & 1023;
    int q = t & 3, j = t >> 2;
    int i0 = q * (ni / 4) + ip2 * 4;
    half_t p[4], qq[4], w[4];
    #pragma unroll
    for (int e = 0; e < 4; ++e) {
        int k = (i0 + e) * NN + j;
        float sg = sigma[k];
        p[e]  = (half_t)(-LOG2E * sg);
        qq[e] = (half_t)(LOG2E * sg * mu[k]);
        w[e]  = (half_t)(W[k] * erev[k]);
    }
    h2 p01 = {p[0], p[1]},  p23 = {p[2], p[3]};
    h2 q01 = {qq[0], qq[1]}, q23 = {qq[2], qq[3]};
    h2 w01 = {w[0], w[1]},  w23 = {w[2], w[3]};
    pq4[gid] = make_uint4(__builtin_bit_cast(unsigned, p01), __builtin_bit_cast(unsigned, q01),
                          __builtin_bit_cast(unsigned, p23), __builtin_bit_cast(unsigned, q23));
    w2[gid]  = make_uint2(__builtin_bit_cast(unsigned, w01), __builtin_bit_cast(unsigned, w23));
}

// Packed-f16 exp2 + quad-shared f32 reciprocal.
// u_k = sigmoid = 1/b_k, b_k = 1 + 2^(p*v+q). num += w*u, den += |w|*u.
__device__ __forceinline__ void proc_quad(uint4 u, uint2 wp, unsigned vv01, unsigned vv23,
                                          v2f& an, v2f& ad)
{
    const h2 CHI = {(half_t)15.0f,   (half_t)15.0f};
    const h2 CLO = {(half_t)-14.0f,  (half_t)-14.0f};
    const h2 MAG = {(half_t)1536.0f, (half_t)1536.0f};
    const h2 C3  = {(half_t)0.0558073f, (half_t)0.0558073f};
    const h2 C2  = {(half_t)0.2401910f, (half_t)0.2401910f};
    const h2 C1  = {(half_t)0.6931474f, (half_t)0.6931474f};
    const h2 C0  = {(half_t)0.9999925f, (half_t)0.9999925f};
    const h2 ONE = {(half_t)1.0f, (half_t)1.0f};
    const us2 EBIAS = {0x3C00, 0x3C00};

    h2 P01 = bch2(u.x), Q01 = bch2(u.y), P23 = bch2(u.z), Q23 = bch2(u.w);
    h2 W01 = bch2(wp.x), W23 = bch2(wp.y);
    h2 V01 = bch2(vv01), V23 = bch2(vv23);

    h2 a01 = __builtin_elementwise_fma(P01, V01, Q01);
    h2 a23 = __builtin_elementwise_fma(P23, V23, Q23);
    a01 = __builtin_elementwise_max(__builtin_elementwise_min(a01, CHI), CLO);
    a23 = __builtin_elementwise_max(__builtin_elementwise_min(a23, CHI), CLO);

    h2 y01 = a01 + MAG,  y23 = a23 + MAG;     // round-to-int via magic add (RNE)
    h2 n01 = y01 - MAG,  n23 = y23 - MAG;     // n = rndne(a), exact
    h2 f01 = a01 - n01,  f23 = a23 - n23;     // f in [-0.5, 0.5], exact

    h2 r01 = __builtin_elementwise_fma(C3, f01, C2);
    h2 r23 = __builtin_elementwise_fma(C3, f23, C2);
    r01 = __builtin_elementwise_fma(r01, f01, C1);
    r23 = __builtin_elementwise_fma(r23, f23, C1);
    r01 = __builtin_elementwise_fma(r01, f01, C0);
    r23 = __builtin_elementwise_fma(r23, f23, C0);

    // 2^n bits: bits(1536+n) = 0x6600+n ; (bits<<10)+0x3C00 = ((n+15)<<10) exactly
    us2 s01 = (us2)(__builtin_bit_cast(us2, y01) << 10) + EBIAS;
    us2 s23 = (us2)(__builtin_bit_cast(us2, y23) << 10) + EBIAS;

    h2 b01 = __builtin_elementwise_fma(r01, __builtin_bit_cast(h2, s01), ONE); // 1 + 2^a
    h2 b23 = __builtin_elementwise_fma(r23, __builtin_bit_cast(h2, s23), ONE);

    h2 t01 = W01 * __builtin_shufflevector(b01, b01, 1, 0);  // {w0*b1, w1*b0}
    h2 t23 = W23 * __builtin_shufflevector(b23, b23, 1, 0);

    float b0 = (float)b01.x, b1 = (float)b01.y;
    float b2 = (float)b23.x, b3 = (float)b23.y;
    float p01f = b0 * b1, p23f = b2 * b3;                    // <= 2^61, f32-safe
    float r4 = __builtin_amdgcn_rcpf(p01f * p23f);           // 1 trans per 4 elems
    float rr01 = r4 * p23f;                                  // = 1/(b0*b1)
    float rr23 = r4 * p01f;                                  // = 1/(b2*b3)

    an.x = fmaf((float)t01.x, rr01, an.x);                   // w0/b0
    an.y = fmaf((float)t01.y, rr01, an.y);                   // w1/b1
    ad.x = fmaf(fabsf((float)t01.x), rr01, ad.x);
    ad.y = fmaf(fabsf((float)t01.y), rr01, ad.y);
    an.x = fmaf((float)t23.x, rr23, an.x);
    an.y = fmaf((float)t23.y, rr23, an.y);
    ad.x = fmaf(fabsf((float)t23.x), rr23, ad.x);
    ad.y = fmaf(fabsf((float)t23.y), rr23, ad.y);
}

// ---------------- main: 1 row/block, 512 blocks, 2 blocks/CU ----------------
// v/x in f16 LDS, replicated 4x (one copy per i-quarter), strides padded so the
// wave's 4 broadcast ds_read_b64 addresses hit disjoint banks.
__global__ __launch_bounds__(1024, 8)
void ltc_f16(const float* __restrict__ inputs, const float* __restrict__ state,
             const uint4* __restrict__ spq, const uint2* __restrict__ sw,
             const uint4* __restrict__ rpq, const uint2* __restrict__ rw,
             const float* __restrict__ vleak, const float* __restrict__ gleak,
             const float* __restrict__ cm, float* __restrict__ out)
{
    __shared__ __align__(16) half_t v_h[2][4][264];   // stride 528B -> bank base 4q
    __shared__ __align__(16) half_t x_h[4][136];      // stride 272B

    const int tid = threadIdx.x;
    const int q   = tid & 3;
    const int j   = tid >> 2;
    const int row = blockIdx.x;

    if (tid < II) {
        half_t xh = (half_t)inputs[row * II + tid];
        #pragma unroll
        for (int c = 0; c < 4; ++c) x_h[c][tid] = xh;
    } else if (tid >= 512 && tid < 512 + NN) {
        half_t vh = (half_t)state[row * NN + (tid - 512)];
        #pragma unroll
        for (int c = 0; c < 4; ++c) v_h[0][c][tid - 512] = vh;
    }
    const float c    = cm[j];
    const float g    = gleak[j];
    const float glvl = g * vleak[j];
    const float denb = c + g;
    __syncthreads();

    // ---- sensory sweep: 8 quads, i in [q*32, q*32+32) ----
    float sn, sd;
    {
        v2f an = {0.f, 0.f}, ad = {0.f, 0.f};
        const uint4* pp = spq + tid;
        const uint2* pw = sw + tid;
        #pragma unroll 2
        for (int ip2 = 0; ip2 < 8; ++ip2, pp += 1024, pw += 1024) {
            uint4 u = *pp;
            uint2 w = *pw;
            uint2 xv = *(const uint2*)&x_h[q][q * 32 + ip2 * 4];
            proc_quad(u, w, xv.x, xv.y, an, ad);
        }
        sn = an.x + an.y;
        sd = ad.x + ad.y;
        sn += __shfl_xor(sn, 1, 64); sn += __shfl_xor(sn, 2, 64);
        sd += __shfl_xor(sd, 1, 64); sd += __shfl_xor(sd, 2, 64);
    }

    // ---- 6 recurrent steps: 16 quads, i in [q*64, q*64+64), 1 barrier/step ----
    int cur = 0;
    for (int step = 0; step < STEPS; ++step) {
        v2f an = {0.f, 0.f}, ad = {0.f, 0.f};
        const uint4* pp = rpq + tid;
        const uint2* pw = rw + tid;
        #pragma unroll 2
        for (int ip2 = 0; ip2 < 16; ++ip2, pp += 1024, pw += 1024) {
            uint4 u = *pp;
            uint2 w = *pw;
            uint2 vv = *(const uint2*)&v_h[cur][q][q * 64 + ip2 * 4];
            proc_quad(u, w, vv.x, vv.y, an, ad);
        }
        float rn = an.x + an.y;
        float rd = ad.x + ad.y;
        rn += __shfl_xor(rn, 1, 64); rn += __shfl_xor(rn, 2, 64);
        rd += __shfl_xor(rd, 1, 64); rd += __shfl_xor(rd, 2, 64);

        float wn = rn + sn, wd = rd + sd;
        float vp = (float)v_h[cur][q][j];
        float vn = (fmaf(c, vp, glvl) + wn) * __builtin_amdgcn_rcpf(denb + wd);
        v_h[cur ^ 1][q][j] = (half_t)vn;              // refresh own replica
        if (q == 0 && step == STEPS - 1) {
            out[row * NN + j] = vn;
            out[BATCH * NN + row * NN + j] = vn;
        }
        __syncthreads();
        cur ^= 1;
    }
}

// ---------------- fallback (no workspace): direct f32, known-correct ----------------
__global__ __launch_bounds__(1024, 4)
void ltc_fallback(const float* __restrict__ inputs, const float* __restrict__ state,
                  const float* __restrict__ s_sigma, const float* __restrict__ s_mu,
                  const float* __restrict__ s_W, const float* __restrict__ s_erev,
                  const float* __restrict__ r_sigma, const float* __restrict__ r_mu,
                  const float* __restrict__ r_W, const float* __restrict__ r_erev,
                  const float* __restrict__ vleak, const float* __restrict__ gleak,
                  const float* __restrict__ cm, float* __restrict__ out)
{
    __shared__ float  v_sh[2][NN];
    __shared__ float  x_sh[2][II];
    __shared__ float2 sens_sh[2][NN];
    __shared__ float2 part[8][NN];

    const int tid  = threadIdx.x;
    const int j    = tid & (NN - 1);
    const int q    = tid >> 8;
    const int row0 = blockIdx.x * 2;

    if (tid < 2 * NN) {
        int r = tid >> 8, cc = tid & (NN - 1);
        v_sh[r][cc] = state[(row0 + r) * NN + cc];
    } else if (tid < 2 * NN + 2 * II) {
        int t = tid - 2 * NN;
        x_sh[t >> 7][t & (II - 1)] = inputs[(row0 + (t >> 7)) * II + (t & (II - 1))];
    }

    const int r2 = tid >> 8;
    float cmv = 0.f, glvl = 0.f, denb = 0.f;
    if (tid < 512) {
        float cc = cm[j], gg = gleak[j];
        cmv = cc; glvl = gg * vleak[j]; denb = cc + gg;
    }
    __syncthreads();

    {
        float sn[2] = {0.f, 0.f}, sd[2] = {0.f, 0.f};
        for (int ii = 0; ii < 32; ++ii) {
            const int i = q * 32 + ii;
            int k = i * NN + j;
            float sg = s_sigma[k];
            float p = -LOG2E * sg, qq = LOG2E * sg * s_mu[k];
            float w = s_W[k] * s_erev[k];
            #pragma unroll
            for (int r = 0; r < 2; ++r) {
                float e = __builtin_amdgcn_exp2f(fmaf(p, x_sh[r][i], qq));
                float t = w * __builtin_amdgcn_rcpf(1.f + e);
                sn[r] += t; sd[r] += fabsf(t);
            }
        }
        part[q * 2 + 0][j] = make_float2(sn[0], sd[0]);
        part[q * 2 + 1][j] = make_float2(sn[1], sd[1]);
    }
    __syncthreads();
    if (tid < 512) {
        float2 a0 = part[0 + r2][j], a1 = part[2 + r2][j], a2 = part[4 + r2][j], a3 = part[6 + r2][j];
        sens_sh[r2][j] = make_float2(a0.x + a1.x + a2.x + a3.x, a0.y + a1.y + a2.y + a3.y);
    }
    __syncthreads();

    for (int step = 0; step < STEPS; ++step) {
        float sn[2] = {0.f, 0.f}, sd[2] = {0.f, 0.f};
        for (int ii = 0; ii < 64; ++ii) {
            const int i = q * 64 + ii;
            int k = i * NN + j;
            float sg = r_sigma[k];
            float p = -LOG2E * sg, qq = LOG2E * sg * r_mu[k];
            float w = r_W[k] * r_erev[k];
            #pragma unroll
            for (int r = 0; r < 2; ++r) {
                float e = __builtin_amdgcn_exp2f(fmaf(p, v_sh[r][i], qq));
                float t = w * __builtin_amdgcn_rcpf(1.f + e);
                sn[r] += t; sd[r] += fabsf(t);
            }
        }
        part[q * 2 + 0][j] = make_float2(sn[0], sd[0]);
        part[q * 2 + 1][j] = make_float2(sn[1], sd[1]);
        __syncthreads();

        if (tid < 512) {
            float2 a0 = part[0 + r2][j], a1 = part[2 + r2][j], a2 = part[4 + r2][j], a3 = part[6 + r2][j];
            float wn = a0.x + a1.x + a2.x + a3.x + sens_sh[r2][j].x;
            float wd = a0.y + a1.y + a2.y + a3.y + sens_sh[r2][j].y;
            float vp = v_sh[r2][j];
            float vn = (fmaf(cmv, vp, glvl) + wn) * __builtin_amdgcn_rcpf(denb + wd);
            v_sh[r2][j] = vn;
            if (step == STEPS - 1) {
                out[(row0 + r2) * NN + j] = vn;
                out[BATCH * NN + (row0 + r2) * NN + j] = vn;
            }
        }
        __syncthreads();
    }
}

extern "C" void kernel_launch(void* const* d_in, const int* in_sizes, int n_in,
                              void* d_out, int out_size, void* d_ws, size_t ws_size,
                              hipStream_t stream)
{
    const float* inputs  = (const float*)d_in[0];
    const float* state   = (const float*)d_in[1];
    const float* s_mu    = (const float*)d_in[2];
    const float* s_sigma = (const float*)d_in[3];
    const float* s_W     = (const float*)d_in[4];
    const float* s_erev  = (const float*)d_in[5];
    const float* mu      = (const float*)d_in[6];
    const float* sigma   = (const float*)d_in[7];
    const float* W       = (const float*)d_in[8];
    const float* erev    = (const float*)d_in[9];
    const float* vleak   = (const float*)d_in[10];
    const float* gleak   = (const float*)d_in[11];
    const float* cm      = (const float*)d_in[12];
    float* out = (float*)d_out;

    // ws layout: rpq4[16384]u4 (256K) | rw2[16384]u2 (128K) | spq4[8192]u4 (128K) | sw2[8192]u2 (64K)
    const size_t need = 16384 * 16 + 16384 * 8 + 8192 * 16 + 8192 * 8;
    if (ws_size >= need) {
        char* p = (char*)d_ws;
        uint4* rpq = (uint4*)p;
        uint2* rw  = (uint2*)(p + 16384 * 16);
        uint4* spq = (uint4*)(p + 16384 * 16 + 16384 * 8);
        uint2* sw  = (uint2*)(p + 16384 * 16 + 16384 * 8 + 8192 * 16);
        pack_f16<<<64, 256, 0, stream>>>(sigma, mu, W, erev, rpq, rw, NN);
        pack_f16<<<32, 256, 0, stream>>>(s_sigma, s_mu, s_W, s_erev, spq, sw, II);
        ltc_f16<<<BATCH, 1024, 0, stream>>>(inputs, state, spq, sw, rpq, rw,
                                            vleak, gleak, cm, out);
    } else {
        ltc_fallback<<<BATCH / 2, 1024, 0, stream>>>(
            inputs, state, s_sigma, s_mu, s_W, s_erev, sigma, mu, W, erev,
            vleak, gleak, cm, out);
    }
}

// Round 6
// 75.247 us; speedup vs baseline: 1.2715x; 1.2715x over previous
//
#include <hip/hip_runtime.h>
#include <stdint.h>

#define NN 256
#define II 128
#define BATCH 512
#define STEPS 6
#define LOG2E 1.4426950408889634f

typedef _Float16 half_t;
typedef _Float16 h2 __attribute__((ext_vector_type(2)));
typedef float v2f __attribute__((ext_vector_type(2)));

// ---------------- pack: per (quad, tid) entry, f16 params ----------------
// Main-kernel mapping: tid in [0,1024), q = tid&3 (i-quarter), j = tid>>2.
// Entry (ip2, tid) covers i = i0..i0+3 with i0 = q*(ni/4) + ip2*4, column j.
// pq4 = { h2{p0,q0}, h2{p1,q1}, h2{p2,q2}, h2{p3,q3} } as dwords,
// w2  = { h2{w0,w1}, h2{w2,w3} };  p = -log2e*sigma, q = log2e*sigma*mu, w = W*erev
__global__ void pack_f16(const float* __restrict__ sigma, const float* __restrict__ mu,
                         const float* __restrict__ W, const float* __restrict__ erev,
                         uint4* __restrict__ pq4, uint2* __restrict__ w2, int ni)
{
    int gid = blockIdx.x * blockDim.x + threadIdx.x;
    int total = (ni / 16) * 1024;
    if (gid >= total) return;
    int ip2 = gid >> 10, t = gid & 1023;
    int q = t & 3, j = t >> 2;
    int i0 = q * (ni / 4) + ip2 * 4;
    unsigned pw[4];
    half_t wa[4];
    #pragma unroll
    for (int e = 0; e < 4; ++e) {
        int k = (i0 + e) * NN + j;
        float sg = sigma[k];
        h2 pq = { (half_t)(-LOG2E * sg), (half_t)(LOG2E * sg * mu[k]) };
        pw[e] = __builtin_bit_cast(unsigned, pq);
        wa[e] = (half_t)(W[k] * erev[k]);
    }
    pq4[gid] = make_uint4(pw[0], pw[1], pw[2], pw[3]);
    h2 w01 = { wa[0], wa[1] }, w23 = { wa[2], wa[3] };
    w2[gid] = make_uint2(__builtin_bit_cast(unsigned, w01),
                         __builtin_bit_cast(unsigned, w23));
}

// R4-proven math: shared reciprocal across the pair; f16 params via v_fma_mix.
__device__ __forceinline__ void proc_pair(unsigned pq0, unsigned pq1, unsigned wp,
                                          float va, float vb, v2f& an, v2f& ad)
{
    h2 P0 = __builtin_bit_cast(h2, pq0);
    h2 P1 = __builtin_bit_cast(h2, pq1);
    h2 Wh = __builtin_bit_cast(h2, wp);
    float e0 = __builtin_amdgcn_exp2f(fmaf((float)P0.x, va, (float)P0.y));
    float e1 = __builtin_amdgcn_exp2f(fmaf((float)P1.x, vb, (float)P1.y));
    float b0 = e0 + 1.f, b1 = e1 + 1.f;
    float rr = __builtin_amdgcn_rcpf(b0 * b1);   // shared reciprocal
    float t0 = fmaf((float)Wh.x, b1, 0.0f);      // v_fma_mix_f32
    float t1 = fmaf((float)Wh.y, b0, 0.0f);
    an.x = fmaf(t0, rr, an.x);
    ad.x = fmaf(fabsf(t0), rr, ad.x);
    an.y = fmaf(t1, rr, an.y);
    ad.y = fmaf(fabsf(t1), rr, ad.y);
}

// ---------------- main: 1 row/block, 512 blocks, 2 blocks/CU ----------------
// LDS replicated 4x (one copy per i-quarter), padded stride (proven 0-conflict).
// Weight loads: compile-time uniform bases (SGPR) + rolling depth-1 prefetch
// that wraps across step boundaries (loads in flight across the barrier).
__global__ __launch_bounds__(1024, 8)
void ltc_f16(const float* __restrict__ inputs, const float* __restrict__ state,
             const uint4* __restrict__ spq, const uint2* __restrict__ sw,
             const uint4* __restrict__ rpq, const uint2* __restrict__ rw,
             const float* __restrict__ vleak, const float* __restrict__ gleak,
             const float* __restrict__ cm, float* __restrict__ out)
{
    __shared__ __align__(16) float v_sh[2][4][NN + 4];
    __shared__ __align__(16) float x_sh[4][II + 4];

    const int tid = threadIdx.x;
    const int q   = tid & 3;
    const int j   = tid >> 2;
    const int row = blockIdx.x;

    if (tid < II) {
        float xv = inputs[row * II + tid];
        #pragma unroll
        for (int c = 0; c < 4; ++c) x_sh[c][tid] = xv;
    } else if (tid >= 512 && tid < 512 + NN) {
        float vv = state[row * NN + (tid - 512)];
        #pragma unroll
        for (int c = 0; c < 4; ++c) v_sh[0][c][tid - 512] = vv;
    }
    const float c    = cm[j];
    const float g    = gleak[j];
    const float glvl = g * vleak[j];
    const float denb = c + g;
    __syncthreads();

    // ---- sensory sweep: 8 quads, i in [q*32, q*32+32) ----
    float sn, sd;
    uint4 ru; uint2 rww;          // rolling prefetch registers (recurrent loop)
    {
        v2f an = {0.f, 0.f}, ad = {0.f, 0.f};
        uint4 ua = spq[tid];
        uint2 wa = sw[tid];
        #pragma unroll
        for (int ip2 = 0; ip2 < 8; ++ip2) {
            uint4 ub; uint2 wb;
            if (ip2 < 7) {                      // compile-time offsets -> SGPR base
                ub = spq[(ip2 + 1) * 1024 + tid];
                wb = sw[(ip2 + 1) * 1024 + tid];
            } else {                            // prefetch step-0 recurrent entry
                ru  = rpq[tid];
                rww = rw[tid];
            }
            float4 xv = *(const float4*)&x_sh[q][q * 32 + ip2 * 4];
            proc_pair(ua.x, ua.y, wa.x, xv.x, xv.y, an, ad);
            proc_pair(ua.z, ua.w, wa.y, xv.z, xv.w, an, ad);
            ua = ub; wa = wb;
        }
        sn = an.x + an.y;
        sd = ad.x + ad.y;
        sn += __shfl_xor(sn, 1, 64); sn += __shfl_xor(sn, 2, 64);
        sd += __shfl_xor(sd, 1, 64); sd += __shfl_xor(sd, 2, 64);
    }

    // ---- 6 recurrent steps: 16 quads, i in [q*64, q*64+64), 1 barrier/step ----
    int cur = 0;
    for (int step = 0; step < STEPS; ++step) {
        v2f an = {0.f, 0.f}, ad = {0.f, 0.f};
        const float* vbase = &v_sh[cur][q][q * 64];
        #pragma unroll 4
        for (int ip2 = 0; ip2 < 16; ++ip2) {
            // prefetch next entry; last iter wraps to entry 0 (= next step's first),
            // so the loads are already in flight when we cross the barrier.
            const int nxt = ((ip2 + 1) & 15) * 1024 + tid;
            uint4 ub = rpq[nxt];
            uint2 wb = rw[nxt];
            float4 vv = *(const float4*)(vbase + ip2 * 4);
            proc_pair(ru.x, ru.y, rww.x, vv.x, vv.y, an, ad);
            proc_pair(ru.z, ru.w, rww.y, vv.z, vv.w, an, ad);
            ru = ub; rww = wb;
        }
        float rn = an.x + an.y;
        float rd = ad.x + ad.y;
        rn += __shfl_xor(rn, 1, 64); rn += __shfl_xor(rn, 2, 64);
        rd += __shfl_xor(rd, 1, 64); rd += __shfl_xor(rd, 2, 64);

        float wn = rn + sn, wd = rd + sd;
        float vp = v_sh[cur][q][j];
        float vn = (fmaf(c, vp, glvl) + wn) * __builtin_amdgcn_rcpf(denb + wd);
        v_sh[cur ^ 1][q][j] = vn;                 // each lane refreshes its replica
        if (q == 0 && step == STEPS - 1) {
            out[row * NN + j] = vn;
            out[BATCH * NN + row * NN + j] = vn;
        }
        __syncthreads();
        cur ^= 1;
    }
}

// ---------------- fallback (no workspace): direct f32, known-correct ----------------
__global__ __launch_bounds__(1024, 4)
void ltc_fallback(const float* __restrict__ inputs, const float* __restrict__ state,
                  const float* __restrict__ s_sigma, const float* __restrict__ s_mu,
                  const float* __restrict__ s_W, const float* __restrict__ s_erev,
                  const float* __restrict__ r_sigma, const float* __restrict__ r_mu,
                  const float* __restrict__ r_W, const float* __restrict__ r_erev,
                  const float* __restrict__ vleak, const float* __restrict__ gleak,
                  const float* __restrict__ cm, float* __restrict__ out)
{
    __shared__ float  v_sh[2][NN];
    __shared__ float  x_sh[2][II];
    __shared__ float2 sens_sh[2][NN];
    __shared__ float2 part[8][NN];

    const int tid  = threadIdx.x;
    const int j    = tid & (NN - 1);
    const int q    = tid >> 8;
    const int row0 = blockIdx.x * 2;

    if (tid < 2 * NN) {
        int r = tid >> 8, cc = tid & (NN - 1);
        v_sh[r][cc] = state[(row0 + r) * NN + cc];
    } else if (tid < 2 * NN + 2 * II) {
        int t = tid - 2 * NN;
        x_sh[t >> 7][t & (II - 1)] = inputs[(row0 + (t >> 7)) * II + (t & (II - 1))];
    }

    const int r2 = tid >> 8;
    float cmv = 0.f, glvl = 0.f, denb = 0.f;
    if (tid < 512) {
        float cc = cm[j], gg = gleak[j];
        cmv = cc; glvl = gg * vleak[j]; denb = cc + gg;
    }
    __syncthreads();

    {
        float sn[2] = {0.f, 0.f}, sd[2] = {0.f, 0.f};
        for (int ii = 0; ii < 32; ++ii) {
            const int i = q * 32 + ii;
            int k = i * NN + j;
            float sg = s_sigma[k];
            float p = -LOG2E * sg, qq = LOG2E * sg * s_mu[k];
            float w = s_W[k] * s_erev[k];
            #pragma unroll
            for (int r = 0; r < 2; ++r) {
                float e = __builtin_amdgcn_exp2f(fmaf(p, x_sh[r][i], qq));
                float t = w * __builtin_amdgcn_rcpf(1.f + e);
                sn[r] += t; sd[r] += fabsf(t);
            }
        }
        part[q * 2 + 0][j] = make_float2(sn[0], sd[0]);
        part[q * 2 + 1][j] = make_float2(sn[1], sd[1]);
    }
    __syncthreads();
    if (tid < 512) {
        float2 a0 = part[0 + r2][j], a1 = part[2 + r2][j], a2 = part[4 + r2][j], a3 = part[6 + r2][j];
        sens_sh[r2][j] = make_float2(a0.x + a1.x + a2.x + a3.x, a0.y + a1.y + a2.y + a3.y);
    }
    __syncthreads();

    for (int step = 0; step < STEPS; ++step) {
        float sn[2] = {0.f, 0.f}, sd[2] = {0.f, 0.f};
        for (int ii = 0; ii < 64; ++ii) {
            const int i = q * 64 + ii;
            int k = i * NN + j;
            float sg = r_sigma[k];
            float p = -LOG2E * sg, qq = LOG2E * sg * r_mu[k];
            float w = r_W[k] * r_erev[k];
            #pragma unroll
            for (int r = 0; r < 2; ++r) {
                float e = __builtin_amdgcn_exp2f(fmaf(p, v_sh[r][i], qq));
                float t = w * __builtin_amdgcn_rcpf(1.f + e);
                sn[r] += t; sd[r] += fabsf(t);
            }
        }
        part[q * 2 + 0][j] = make_float2(sn[0], sd[0]);
        part[q * 2 + 1][j] = make_float2(sn[1], sd[1]);
        __syncthreads();

        if (tid < 512) {
            float2 a0 = part[0 + r2][j], a1 = part[2 + r2][j], a2 = part[4 + r2][j], a3 = part[6 + r2][j];
            float wn = a0.x + a1.x + a2.x + a3.x + sens_sh[r2][j].x;
            float wd = a0.y + a1.y + a2.y + a3.y + sens_sh[r2][j].y;
            float vp = v_sh[r2][j];
            float vn = (fmaf(cmv, vp, glvl) + wn) * __builtin_amdgcn_rcpf(denb + wd);
            v_sh[r2][j] = vn;
            if (step == STEPS - 1) {
                out[(row0 + r2) * NN + j] = vn;
                out[BATCH * NN + (row0 + r2) * NN + j] = vn;
            }
        }
        __syncthreads();
    }
}

extern "C" void kernel_launch(void* const* d_in, const int* in_sizes, int n_in,
                              void* d_out, int out_size, void* d_ws, size_t ws_size,
                              hipStream_t stream)
{
    const float* inputs  = (const float*)d_in[0];
    const float* state   = (const float*)d_in[1];
    const float* s_mu    = (const float*)d_in[2];
    const float* s_sigma = (const float*)d_in[3];
    const float* s_W     = (const float*)d_in[4];
    const float* s_erev  = (const float*)d_in[5];
    const float* mu      = (const float*)d_in[6];
    const float* sigma   = (const float*)d_in[7];
    const float* W       = (const float*)d_in[8];
    const float* erev    = (const float*)d_in[9];
    const float* vleak   = (const float*)d_in[10];
    const float* gleak   = (const float*)d_in[11];
    const float* cm      = (const float*)d_in[12];
    float* out = (float*)d_out;

    // ws layout: rpq4[16384]u4 (256K) | rw2[16384]u2 (128K) | spq4[8192]u4 (128K) | sw2[8192]u2 (64K)
    const size_t need = 16384 * 16 + 16384 * 8 + 8192 * 16 + 8192 * 8;
    if (ws_size >= need) {
        char* p = (char*)d_ws;
        uint4* rpq = (uint4*)p;
        uint2* rw  = (uint2*)(p + 16384 * 16);
        uint4* spq = (uint4*)(p + 16384 * 16 + 16384 * 8);
        uint2* sw  = (uint2*)(p + 16384 * 16 + 16384 * 8 + 8192 * 16);
        pack_f16<<<64, 256, 0, stream>>>(sigma, mu, W, erev, rpq, rw, NN);
        pack_f16<<<32, 256, 0, stream>>>(s_sigma, s_mu, s_W, s_erev, spq, sw, II);
        ltc_f16<<<BATCH, 1024, 0, stream>>>(inputs, state, spq, sw, rpq, rw,
                                            vleak, gleak, cm, out);
    } else {
        ltc_fallback<<<BATCH / 2, 1024, 0, stream>>>(
            inputs, state, s_sigma, s_mu, s_W, s_erev, sigma, mu, W, erev,
            vleak, gleak, cm, out);
    }
}